// Round 7
// baseline (207.371 us; speedup 1.0000x reference)
//
#include <hip/hip_runtime.h>
#include <hip/hip_bf16.h>

typedef __hip_bfloat16 bf16;
typedef __attribute__((ext_vector_type(8))) short short8;

static constexpr int NPOS = 65536;  // 64*64*16

// bf16 bits (as short) -> float
__device__ __forceinline__ float bs2f(short s) {
  union { float f; unsigned u; } cv;
  cv.u = ((unsigned)(unsigned short)s) << 16;
  return cv.f;
}
// float -> bf16 bits (as short), RNE
__device__ __forceinline__ short f2bs(float f) {
  bf16 b = __float2bfloat16(f);
  short r;
  __builtin_memcpy(&r, &b, 2);
  return r;
}

// trilinear upsample of channel slab xc (32,32,8) evaluated at output (h,w,z)
__device__ __forceinline__ float upsample_at(const float* __restrict__ xc,
                                             int h, int w, int z) {
  float fh = (float)h * (31.0f / 63.0f);
  float fw = (float)w * (31.0f / 63.0f);
  float fz = (float)z * (7.0f / 15.0f);
  int ih = (int)fh; if (ih > 30) ih = 30;
  int iw = (int)fw; if (iw > 30) iw = 30;
  int iz = (int)fz; if (iz > 6) iz = 6;
  float wh = fh - (float)ih, ww = fw - (float)iw, wz = fz - (float)iz;
  const float* xb = xc + ih * 256 + iw * 8 + iz;
  float v000 = xb[0],   v001 = xb[1];
  float v010 = xb[8],   v011 = xb[9];
  float v100 = xb[256], v101 = xb[257];
  float v110 = xb[264], v111 = xb[265];
  float v00 = v000 * (1.f - wz) + v001 * wz;
  float v01 = v010 * (1.f - wz) + v011 * wz;
  float v10 = v100 * (1.f - wz) + v101 * wz;
  float v11 = v110 * (1.f - wz) + v111 * wz;
  float v0 = v00 * (1.f - ww) + v01 * ww;
  float v1 = v10 * (1.f - ww) + v11 * ww;
  return v0 * (1.f - wh) + v1 * wh;
}

// K1a: partial instance-norm sums + xu materialization (bf16).
// blocks 0..511: upsampled-x channel c=b>>3, chunk b&7. blocks 512..1023: skip.
__global__ __launch_bounds__(256) void k_partial(const float* __restrict__ x,
                                                 const float* __restrict__ skip,
                                                 bf16* __restrict__ xu,
                                                 float* __restrict__ partials) {
  __shared__ float s1[256];
  __shared__ float s2[256];
  int b = blockIdx.x, tid = threadIdx.x;
  float sum = 0.f, sq = 0.f;
  if (b < 512) {
    int c = b >> 3, base = (b & 7) * 8192;
    const float* xc = x + c * 8192;
    bf16* xo = xu + (size_t)c * NPOS;
    for (int i = tid; i < 8192; i += 256) {
      int pos = base + i;
      int h = pos >> 10, w = (pos >> 4) & 63, z = pos & 15;
      float v = upsample_at(xc, h, w, z);
      xo[pos] = __float2bfloat16(v);
      sum += v; sq += v * v;
    }
  } else {
    int bb = b - 512;
    const float* p = skip + (size_t)(bb >> 3) * NPOS + (bb & 7) * 8192;
    for (int i = tid; i < 8192; i += 256) { float v = p[i]; sum += v; sq += v * v; }
  }
  s1[tid] = sum; s2[tid] = sq;
  __syncthreads();
  for (int s = 128; s > 0; s >>= 1) {
    if (tid < s) { s1[tid] += s1[tid + s]; s2[tid] += s2[tid + s]; }
    __syncthreads();
  }
  if (tid == 0) { partials[2 * b] = s1[0]; partials[2 * b + 1] = s2[0]; }
}

// K1b: finalize stats. [mean_xu(64), rstd_xu(64), mean_sk(64), rstd_sk(64)]
__global__ __launch_bounds__(128) void k_finalize(const float* __restrict__ partials,
                                                  float* __restrict__ stats) {
  int t = threadIdx.x;
  int base = (t < 64) ? t * 8 : 512 + (t - 64) * 8;
  float sum = 0.f, sq = 0.f;
#pragma unroll
  for (int j = 0; j < 8; j++) {
    sum += partials[2 * (base + j)];
    sq  += partials[2 * (base + j) + 1];
  }
  float m = sum * (1.0f / NPOS);
  float var = sq * (1.0f / NPOS) - m * m;
  int off = (t < 64) ? 0 : 128;
  int c = t & 63;
  stats[off + c] = m;
  stats[off + 64 + c] = rsqrtf(var + 1e-5f);
}

// K2: norm + K/V/Q projections. k/v/q pos-major bf16 (q pre-scaled by 8^-0.5).
// 64 positions per block; one shared 16 KB weight buffer, three passes.
__global__ __launch_bounds__(256, 5) void k_proj_kvq(
    const bf16* __restrict__ xu, const float* __restrict__ skip,
    const float* __restrict__ stats,
    const float* __restrict__ Wk, const float* __restrict__ bk,
    const float* __restrict__ Wv, const float* __restrict__ bv,
    const float* __restrict__ Wq, const float* __restrict__ bq,
    bf16* __restrict__ kbuf, bf16* __restrict__ vbuf, bf16* __restrict__ qbuf) {
  __shared__ float xt[4096];    // [c][t] 64x64 normalized values
  __shared__ float wbuf[4096];  // Wk -> Wv -> Wq
  int tid = threadIdx.x;
  int p0 = blockIdx.x * 64;
  for (int i = tid; i < 4096; i += 256) {
    wbuf[i] = Wk[i];
    int c = i >> 6, t = i & 63;
    xt[i] = (bs2f(*(const short*)(xu + (size_t)c * NPOS + p0 + t)) - stats[c]) *
            stats[64 + c];
  }
  __syncthreads();
  int t = tid & 63;
  int j0 = (tid >> 6) * 16;  // this thread owns outputs j0..j0+15
  size_t p = (size_t)(p0 + t);
  float a0[8], a1[8];
  short8 s0, s1v;

  // pass 1: K
#pragma unroll
  for (int u = 0; u < 8; u++) { a0[u] = bk[j0 + u]; a1[u] = bk[j0 + 8 + u]; }
  for (int c = 0; c < 64; c++) {
    float xv = xt[c * 64 + t];
    const float* wr = &wbuf[c * 64 + j0];
#pragma unroll
    for (int u = 0; u < 8; u++) { a0[u] += xv * wr[u]; a1[u] += xv * wr[8 + u]; }
  }
#pragma unroll
  for (int u = 0; u < 8; u++) { s0[u] = f2bs(a0[u]); s1v[u] = f2bs(a1[u]); }
  *(short8*)(kbuf + p * 64 + j0) = s0;
  *(short8*)(kbuf + p * 64 + j0 + 8) = s1v;

  __syncthreads();
  for (int i = tid; i < 4096; i += 256) wbuf[i] = Wv[i];
  __syncthreads();

  // pass 2: V
#pragma unroll
  for (int u = 0; u < 8; u++) { a0[u] = bv[j0 + u]; a1[u] = bv[j0 + 8 + u]; }
  for (int c = 0; c < 64; c++) {
    float xv = xt[c * 64 + t];
    const float* wr = &wbuf[c * 64 + j0];
#pragma unroll
    for (int u = 0; u < 8; u++) { a0[u] += xv * wr[u]; a1[u] += xv * wr[8 + u]; }
  }
#pragma unroll
  for (int u = 0; u < 8; u++) { s0[u] = f2bs(a0[u]); s1v[u] = f2bs(a1[u]); }
  *(short8*)(vbuf + p * 64 + j0) = s0;
  *(short8*)(vbuf + p * 64 + j0 + 8) = s1v;

  __syncthreads();
  for (int i = tid; i < 4096; i += 256) {
    wbuf[i] = Wq[i];
    int c = i >> 6, tt = i & 63;
    xt[i] = (skip[(size_t)c * NPOS + p0 + tt] - stats[128 + c]) * stats[192 + c];
  }
  __syncthreads();

  // pass 3: Q (pre-scaled)
  const float scale = 0.35355339059327373f;  // 8^-0.5
#pragma unroll
  for (int u = 0; u < 8; u++) { a0[u] = bq[j0 + u]; a1[u] = bq[j0 + 8 + u]; }
  for (int c = 0; c < 64; c++) {
    float xv = xt[c * 64 + t];
    const float* wr = &wbuf[c * 64 + j0];
#pragma unroll
    for (int u = 0; u < 8; u++) { a0[u] += xv * wr[u]; a1[u] += xv * wr[8 + u]; }
  }
#pragma unroll
  for (int u = 0; u < 8; u++) {
    s0[u] = f2bs(a0[u] * scale); s1v[u] = f2bs(a1[u] * scale);
  }
  *(short8*)(qbuf + p * 64 + j0) = s0;
  *(short8*)(qbuf + p * 64 + j0 + 8) = s1v;
}

// K3: 27-neighbor attention (3 groups of 9, batched softmax) + output
// projection. 32 positions/block, 8 threads per position (one per head).
__global__ __launch_bounds__(256, 5) void k_attn(
    const bf16* __restrict__ qbuf, const bf16* __restrict__ kbuf,
    const bf16* __restrict__ vbuf,
    const float* __restrict__ Wo, const float* __restrict__ bo,
    const float* __restrict__ rpb, float* __restrict__ out) {
  __shared__ float wo[4096];
  __shared__ float rp[1000];
  __shared__ float bol[64];
  __shared__ float oT[32 * 65];  // [pos][j], padded
  int tid = threadIdx.x;
  int p0 = blockIdx.x * 32;
  for (int i = tid; i < 4096; i += 256) wo[i] = Wo[i];
  for (int i = tid; i < 1000; i += 256) rp[i] = rpb[i];
  if (tid < 64) bol[tid] = bo[tid];
  __syncthreads();

  int head = tid & 7, pp = tid >> 3;
  int p = p0 + pp;
  int h = p >> 10, w = (p >> 4) & 63, z = p & 15;

  short8 q8 = *(const short8*)(qbuf + (size_t)p * 64 + head * 8);
  float q[8];
#pragma unroll
  for (int d = 0; d < 8; d++) q[d] = bs2f(q8[d]);

  int sh = h - 1; if (sh < 0) sh = 0; if (sh > 61) sh = 61;
  int sw = w - 1; if (sw < 0) sw = 0; if (sw > 61) sw = 61;
  int sz = z - 1; if (sz < 0) sz = 0; if (sz > 13) sz = 13;

  float mrun = -1e30f, lrun = 0.f;
  float oa[8];
#pragma unroll
  for (int d = 0; d < 8; d++) oa[d] = 0.f;
  const float* rph = &rp[head * 125];

  for (int kh = 0; kh < 3; kh++) {
    int nh = sh + kh;
    int rh = nh - h + 2;
    size_t rowbase = (size_t)nh * 1024;
    // 9 independent logits (loads pipeline; no serial exp chain)
    float s[9];
#pragma unroll
    for (int j = 0; j < 9; j++) {
      int kw = j / 3, kz = j % 3;
      int nw = sw + kw, nz = sz + kz;
      size_t np_ = rowbase + (size_t)(nw * 16 + nz);
      short8 k8 = *(const short8*)(kbuf + np_ * 64 + head * 8);
      float sv = q[0] * bs2f(k8[0]) + q[1] * bs2f(k8[1]) +
                 q[2] * bs2f(k8[2]) + q[3] * bs2f(k8[3]) +
                 q[4] * bs2f(k8[4]) + q[5] * bs2f(k8[5]) +
                 q[6] * bs2f(k8[6]) + q[7] * bs2f(k8[7]);
      int rw = nw - w + 2, rz = nz - z + 2;
      s[j] = sv + rph[(rh * 5 + rw) * 5 + rz];
    }
    // group max (tree)
    float m01 = fmaxf(s[0], s[1]), m23 = fmaxf(s[2], s[3]);
    float m45 = fmaxf(s[4], s[5]), m67 = fmaxf(s[6], s[7]);
    float gm = fmaxf(fmaxf(fmaxf(m01, m23), fmaxf(m45, m67)), s[8]);
    float nm = fmaxf(mrun, gm);
    float alpha = __expf(mrun - nm);
    lrun *= alpha;
#pragma unroll
    for (int d = 0; d < 8; d++) oa[d] *= alpha;
    // batched exps + independent v accumulation
#pragma unroll
    for (int j = 0; j < 9; j++) {
      int kw = j / 3, kz = j % 3;
      int nw = sw + kw, nz = sz + kz;
      size_t np_ = rowbase + (size_t)(nw * 16 + nz);
      float pw = __expf(s[j] - nm);
      lrun += pw;
      short8 v8 = *(const short8*)(vbuf + np_ * 64 + head * 8);
#pragma unroll
      for (int d = 0; d < 8; d++) oa[d] += pw * bs2f(v8[d]);
    }
    mrun = nm;
  }
  float inv = 1.0f / lrun;
#pragma unroll
  for (int d = 0; d < 8; d++) oT[pp * 65 + head * 8 + d] = oa[d] * inv;
  __syncthreads();

  // output projection: group g -> channels g*8..g*8+7, lane l = position
  int g = tid >> 5, l = tid & 31;
  float acc[8];
#pragma unroll
  for (int u = 0; u < 8; u++) acc[u] = bol[g * 8 + u];
  for (int j = 0; j < 64; j++) {
    float ov = oT[l * 65 + j];
    const float* wr = &wo[j * 64 + g * 8];
#pragma unroll
    for (int u = 0; u < 8; u++) acc[u] += ov * wr[u];
  }
#pragma unroll
  for (int u = 0; u < 8; u++)
    out[(size_t)(g * 8 + u) * NPOS + p0 + l] = acc[u];
}

extern "C" void kernel_launch(void* const* d_in, const int* in_sizes, int n_in,
                              void* d_out, int out_size, void* d_ws, size_t ws_size,
                              hipStream_t stream) {
  const float* x    = (const float*)d_in[0];
  const float* skip = (const float*)d_in[1];
  const float* Wq   = (const float*)d_in[2];
  const float* bq   = (const float*)d_in[3];
  const float* Wk   = (const float*)d_in[4];
  const float* bk   = (const float*)d_in[5];
  const float* Wv   = (const float*)d_in[6];
  const float* bv   = (const float*)d_in[7];
  const float* Wo   = (const float*)d_in[8];
  const float* bo   = (const float*)d_in[9];
  const float* rpb  = (const float*)d_in[10];

  // ws layout (total 32 MB + ~12 KB):
  bf16* xu       = (bf16*)d_ws;                                  // 8 MB
  bf16* kbuf     = (bf16*)((char*)d_ws + ((size_t)8 << 20));     // 8 MB
  bf16* vbuf     = (bf16*)((char*)d_ws + ((size_t)16 << 20));    // 8 MB
  bf16* qbuf     = (bf16*)((char*)d_ws + ((size_t)24 << 20));    // 8 MB
  float* stats   = (float*)((char*)d_ws + ((size_t)32 << 20));   // 256 fp32
  float* partials = stats + 256;                                 // 2048 fp32
  float* out = (float*)d_out;

  hipLaunchKernelGGL(k_partial, dim3(1024), dim3(256), 0, stream, x, skip, xu,
                     partials);
  hipLaunchKernelGGL(k_finalize, dim3(1), dim3(128), 0, stream, partials, stats);
  hipLaunchKernelGGL(k_proj_kvq, dim3(1024), dim3(256), 0, stream, xu, skip,
                     stats, Wk, bk, Wv, bv, Wq, bq, kbuf, vbuf, qbuf);
  hipLaunchKernelGGL(k_attn, dim3(2048), dim3(256), 0, stream, qbuf, kbuf, vbuf,
                     Wo, bo, rpb, out);
}

// Round 8
// 161.048 us; speedup vs baseline: 1.2876x; 1.2876x over previous
//
#include <hip/hip_runtime.h>
#include <hip/hip_bf16.h>

typedef __hip_bfloat16 bf16;
typedef __attribute__((ext_vector_type(8))) short short8;

static constexpr int NPOS = 65536;  // 64*64*16

__device__ __forceinline__ float bs2f(short s) {
  union { float f; unsigned u; } cv;
  cv.u = ((unsigned)(unsigned short)s) << 16;
  return cv.f;
}
__device__ __forceinline__ short f2bs(float f) {
  bf16 b = __float2bfloat16(f);
  short r;
  __builtin_memcpy(&r, &b, 2);
  return r;
}

// trilinear upsample of channel slab xc (32,32,8) at output (h,w,z)
__device__ __forceinline__ float upsample_at(const float* __restrict__ xc,
                                             int h, int w, int z) {
  float fh = (float)h * (31.0f / 63.0f);
  float fw = (float)w * (31.0f / 63.0f);
  float fz = (float)z * (7.0f / 15.0f);
  int ih = (int)fh; if (ih > 30) ih = 30;
  int iw = (int)fw; if (iw > 30) iw = 30;
  int iz = (int)fz; if (iz > 6) iz = 6;
  float wh = fh - (float)ih, ww = fw - (float)iw, wz = fz - (float)iz;
  const float* xb = xc + ih * 256 + iw * 8 + iz;
  float v000 = xb[0],   v001 = xb[1];
  float v010 = xb[8],   v011 = xb[9];
  float v100 = xb[256], v101 = xb[257];
  float v110 = xb[264], v111 = xb[265];
  float v00 = v000 * (1.f - wz) + v001 * wz;
  float v01 = v010 * (1.f - wz) + v011 * wz;
  float v10 = v100 * (1.f - wz) + v101 * wz;
  float v11 = v110 * (1.f - wz) + v111 * wz;
  float v0 = v00 * (1.f - ww) + v01 * ww;
  float v1 = v10 * (1.f - ww) + v11 * ww;
  return v0 * (1.f - wh) + v1 * wh;
}

// K1a: partial sums + xu materialization (bf16). 2048 blocks:
// 0..1023 -> x channel b>>4 chunk b&15; 1024..2047 -> skip (float4 reads).
__global__ __launch_bounds__(256) void k_partial(const float* __restrict__ x,
                                                 const float* __restrict__ skip,
                                                 bf16* __restrict__ xu,
                                                 float* __restrict__ partials) {
  __shared__ float s1[256];
  __shared__ float s2[256];
  int b = blockIdx.x, tid = threadIdx.x;
  float sum = 0.f, sq = 0.f;
  if (b < 1024) {
    int c = b >> 4, base = (b & 15) * 4096;
    const float* xc = x + c * 8192;
    bf16* xo = xu + (size_t)c * NPOS;
    for (int i = tid; i < 4096; i += 256) {
      int pos = base + i;
      int h = pos >> 10, w = (pos >> 4) & 63, z = pos & 15;
      float v = upsample_at(xc, h, w, z);
      xo[pos] = __float2bfloat16(v);
      sum += v; sq += v * v;
    }
  } else {
    int bb = b - 1024;
    const float4* p =
        (const float4*)(skip + (size_t)(bb >> 4) * NPOS + (bb & 15) * 4096);
    for (int i = tid; i < 1024; i += 256) {
      float4 v = p[i];
      sum += v.x + v.y + v.z + v.w;
      sq += v.x * v.x + v.y * v.y + v.z * v.z + v.w * v.w;
    }
  }
  s1[tid] = sum; s2[tid] = sq;
  __syncthreads();
  for (int s = 128; s > 0; s >>= 1) {
    if (tid < s) { s1[tid] += s1[tid + s]; s2[tid] += s2[tid + s]; }
    __syncthreads();
  }
  if (tid == 0) { partials[2 * b] = s1[0]; partials[2 * b + 1] = s2[0]; }
}

// K1b: finalize. stats: [mean_xu(64), rstd_xu(64), mean_sk(64), rstd_sk(64)]
__global__ __launch_bounds__(128) void k_finalize(const float* __restrict__ partials,
                                                  float* __restrict__ stats) {
  int t = threadIdx.x;
  int base = (t < 64) ? t * 16 : 1024 + (t - 64) * 16;
  float sum = 0.f, sq = 0.f;
#pragma unroll
  for (int j = 0; j < 16; j++) {
    sum += partials[2 * (base + j)];
    sq  += partials[2 * (base + j) + 1];
  }
  float m = sum * (1.0f / NPOS);
  float var = sq * (1.0f / NPOS) - m * m;
  int off = (t < 64) ? 0 : 128;
  int c = t & 63;
  stats[off + c] = m;
  stats[off + 64 + c] = rsqrtf(var + 1e-5f);
}

// K2: norm + K/V/Q projections. Weights read via wave-uniform scalar loads
// (no weight LDS). xt tile in LDS. q pre-scaled by 8^-0.5.
__global__ __launch_bounds__(256) void k_proj_kvq(
    const bf16* __restrict__ xu, const float* __restrict__ skip,
    const float* __restrict__ stats,
    const float* __restrict__ Wk, const float* __restrict__ bk,
    const float* __restrict__ Wv, const float* __restrict__ bv,
    const float* __restrict__ Wq, const float* __restrict__ bq,
    bf16* __restrict__ kbuf, bf16* __restrict__ vbuf, bf16* __restrict__ qbuf) {
  __shared__ float xt[4096];  // [c][t] 64x64 normalized values
  int tid = threadIdx.x;
  int p0 = blockIdx.x * 64;
  // stage normalized xu tile (bf16x8 vector loads)
  for (int ii = tid; ii < 512; ii += 256) {
    int c = ii >> 3, t0 = (ii & 7) * 8;
    short8 v8 = *(const short8*)(xu + (size_t)c * NPOS + p0 + t0);
    float m = stats[c], r = stats[64 + c];
#pragma unroll
    for (int u = 0; u < 8; u++) xt[c * 64 + t0 + u] = (bs2f(v8[u]) - m) * r;
  }
  __syncthreads();
  int t = tid & 63;
  int j0 = __builtin_amdgcn_readfirstlane((tid >> 6) * 16);  // wave-uniform
  size_t p = (size_t)(p0 + t);
  float a[16];
  short8 s0, s1v;

  // pass 1: K
#pragma unroll
  for (int u = 0; u < 16; u++) a[u] = bk[j0 + u];
  for (int c = 0; c < 64; c++) {
    float xv = xt[c * 64 + t];
    const float* wr = Wk + c * 64 + j0;  // uniform -> s_load
#pragma unroll
    for (int u = 0; u < 16; u++) a[u] += xv * wr[u];
  }
#pragma unroll
  for (int u = 0; u < 8; u++) { s0[u] = f2bs(a[u]); s1v[u] = f2bs(a[8 + u]); }
  *(short8*)(kbuf + p * 64 + j0) = s0;
  *(short8*)(kbuf + p * 64 + j0 + 8) = s1v;

  // pass 2: V (xt unchanged)
#pragma unroll
  for (int u = 0; u < 16; u++) a[u] = bv[j0 + u];
  for (int c = 0; c < 64; c++) {
    float xv = xt[c * 64 + t];
    const float* wr = Wv + c * 64 + j0;
#pragma unroll
    for (int u = 0; u < 16; u++) a[u] += xv * wr[u];
  }
#pragma unroll
  for (int u = 0; u < 8; u++) { s0[u] = f2bs(a[u]); s1v[u] = f2bs(a[8 + u]); }
  *(short8*)(vbuf + p * 64 + j0) = s0;
  *(short8*)(vbuf + p * 64 + j0 + 8) = s1v;

  // restage xt with normalized skip (float4 loads)
  __syncthreads();
  for (int ii = tid; ii < 1024; ii += 256) {
    int c = ii >> 4, t0 = (ii & 15) * 4;
    float4 v = *(const float4*)(skip + (size_t)c * NPOS + p0 + t0);
    float m = stats[128 + c], r = stats[192 + c];
    xt[c * 64 + t0]     = (v.x - m) * r;
    xt[c * 64 + t0 + 1] = (v.y - m) * r;
    xt[c * 64 + t0 + 2] = (v.z - m) * r;
    xt[c * 64 + t0 + 3] = (v.w - m) * r;
  }
  __syncthreads();

  // pass 3: Q (pre-scaled)
  const float scale = 0.35355339059327373f;  // 8^-0.5
#pragma unroll
  for (int u = 0; u < 16; u++) a[u] = bq[j0 + u];
  for (int c = 0; c < 64; c++) {
    float xv = xt[c * 64 + t];
    const float* wr = Wq + c * 64 + j0;
#pragma unroll
    for (int u = 0; u < 16; u++) a[u] += xv * wr[u];
  }
#pragma unroll
  for (int u = 0; u < 8; u++) {
    s0[u] = f2bs(a[u] * scale); s1v[u] = f2bs(a[8 + u] * scale);
  }
  *(short8*)(qbuf + p * 64 + j0) = s0;
  *(short8*)(qbuf + p * 64 + j0 + 8) = s1v;
}

// K3: 27-neighbor attention + output projection. 512 threads, 64 positions
// per block. XCD swizzle: each XCD's 128 blocks cover a contiguous h-slab so
// the k/v halo (~2.6 MB) stays L2-resident per XCD. Out-proj: one wave = 8
// channels -> Wo reads wave-uniform (scalar loads).
__global__ __launch_bounds__(512, 4) void k_attn(
    const bf16* __restrict__ qbuf, const bf16* __restrict__ kbuf,
    const bf16* __restrict__ vbuf,
    const float* __restrict__ Wo, const float* __restrict__ bo,
    const float* __restrict__ rpb, float* __restrict__ out) {
  __shared__ float rp[1000];
  __shared__ float oT[64 * 65];  // [pos][j], stride 65 (conflict-free)
  int tid = threadIdx.x;
  int b = blockIdx.x;
  int sb = ((b & 7) << 7) + (b >> 3);  // XCD-contiguous spatial swizzle
  int p0 = sb * 64;
  for (int i = tid; i < 1000; i += 512) rp[i] = rpb[i];
  __syncthreads();

  int head = tid & 7, pp = tid >> 3;
  int p = p0 + pp;
  int h = p >> 10, w = (p >> 4) & 63, z = p & 15;

  short8 q8 = *(const short8*)(qbuf + (size_t)p * 64 + head * 8);
  float q[8];
#pragma unroll
  for (int d = 0; d < 8; d++) q[d] = bs2f(q8[d]);

  int sh = h - 1; if (sh < 0) sh = 0; if (sh > 61) sh = 61;
  int sw = w - 1; if (sw < 0) sw = 0; if (sw > 61) sw = 61;
  int sz = z - 1; if (sz < 0) sz = 0; if (sz > 13) sz = 13;

  float mrun = -1e30f, lrun = 0.f;
  float oa[8];
#pragma unroll
  for (int d = 0; d < 8; d++) oa[d] = 0.f;
  const float* rph = &rp[head * 125];

  for (int kh = 0; kh < 3; kh++) {
    int nh = sh + kh;
    int rh = nh - h + 2;
    size_t rowbase = (size_t)nh * 1024;
    float s[9];
#pragma unroll
    for (int j = 0; j < 9; j++) {
      int kw = j / 3, kz = j % 3;
      int nw = sw + kw, nz = sz + kz;
      size_t np_ = rowbase + (size_t)(nw * 16 + nz);
      short8 k8 = *(const short8*)(kbuf + np_ * 64 + head * 8);
      float sv = q[0] * bs2f(k8[0]) + q[1] * bs2f(k8[1]) +
                 q[2] * bs2f(k8[2]) + q[3] * bs2f(k8[3]) +
                 q[4] * bs2f(k8[4]) + q[5] * bs2f(k8[5]) +
                 q[6] * bs2f(k8[6]) + q[7] * bs2f(k8[7]);
      int rw = nw - w + 2, rz = nz - z + 2;
      s[j] = sv + rph[(rh * 5 + rw) * 5 + rz];
    }
    float m01 = fmaxf(s[0], s[1]), m23 = fmaxf(s[2], s[3]);
    float m45 = fmaxf(s[4], s[5]), m67 = fmaxf(s[6], s[7]);
    float gm = fmaxf(fmaxf(fmaxf(m01, m23), fmaxf(m45, m67)), s[8]);
    float nm = fmaxf(mrun, gm);
    float alpha = __expf(mrun - nm);
    lrun *= alpha;
#pragma unroll
    for (int d = 0; d < 8; d++) oa[d] *= alpha;
#pragma unroll
    for (int j = 0; j < 9; j++) {
      int kw = j / 3, kz = j % 3;
      int nw = sw + kw, nz = sz + kz;
      size_t np_ = rowbase + (size_t)(nw * 16 + nz);
      float pw = __expf(s[j] - nm);
      lrun += pw;
      short8 v8 = *(const short8*)(vbuf + np_ * 64 + head * 8);
#pragma unroll
      for (int d = 0; d < 8; d++) oa[d] += pw * bs2f(v8[d]);
    }
    mrun = nm;
  }
  float inv = 1.0f / lrun;
#pragma unroll
  for (int d = 0; d < 8; d++) oT[pp * 65 + head * 8 + d] = oa[d] * inv;
  __syncthreads();

  // output projection: wave wid -> channels wid*8..wid*8+7, lane l = position
  int wid = __builtin_amdgcn_readfirstlane(tid >> 6);  // wave-uniform
  int l = tid & 63;
  float acc[8];
#pragma unroll
  for (int u = 0; u < 8; u++) acc[u] = bo[wid * 8 + u];  // uniform s_load
  for (int j = 0; j < 64; j++) {
    float ov = oT[l * 65 + j];
    const float* wr = Wo + j * 64 + wid * 8;  // uniform -> s_load
#pragma unroll
    for (int u = 0; u < 8; u++) acc[u] += ov * wr[u];
  }
#pragma unroll
  for (int u = 0; u < 8; u++)
    out[(size_t)(wid * 8 + u) * NPOS + p0 + l] = acc[u];
}

extern "C" void kernel_launch(void* const* d_in, const int* in_sizes, int n_in,
                              void* d_out, int out_size, void* d_ws, size_t ws_size,
                              hipStream_t stream) {
  const float* x    = (const float*)d_in[0];
  const float* skip = (const float*)d_in[1];
  const float* Wq   = (const float*)d_in[2];
  const float* bq   = (const float*)d_in[3];
  const float* Wk   = (const float*)d_in[4];
  const float* bk   = (const float*)d_in[5];
  const float* Wv   = (const float*)d_in[6];
  const float* bv   = (const float*)d_in[7];
  const float* Wo   = (const float*)d_in[8];
  const float* bo   = (const float*)d_in[9];
  const float* rpb  = (const float*)d_in[10];

  // ws layout (32 MB + ~18 KB):
  bf16* xu        = (bf16*)d_ws;                                 // 8 MB
  bf16* kbuf      = (bf16*)((char*)d_ws + ((size_t)8 << 20));    // 8 MB
  bf16* vbuf      = (bf16*)((char*)d_ws + ((size_t)16 << 20));   // 8 MB
  bf16* qbuf      = (bf16*)((char*)d_ws + ((size_t)24 << 20));   // 8 MB
  float* stats    = (float*)((char*)d_ws + ((size_t)32 << 20));  // 256 fp32
  float* partials = stats + 256;                                 // 4096 fp32
  float* out = (float*)d_out;

  hipLaunchKernelGGL(k_partial, dim3(2048), dim3(256), 0, stream, x, skip, xu,
                     partials);
  hipLaunchKernelGGL(k_finalize, dim3(1), dim3(128), 0, stream, partials, stats);
  hipLaunchKernelGGL(k_proj_kvq, dim3(1024), dim3(256), 0, stream, xu, skip,
                     stats, Wk, bk, Wv, bv, Wq, bq, kbuf, vbuf, qbuf);
  hipLaunchKernelGGL(k_attn, dim3(1024), dim3(512), 0, stream, qbuf, kbuf, vbuf,
                     Wo, bo, rpb, out);
}